// Round 5
// baseline (855.812 us; speedup 1.0000x reference)
//
#include <hip/hip_runtime.h>
#include <hip/hip_bf16.h>

#define N_FULL 200000
#define N_SUB  80000
#define E_NUM  800000
#define IN_DIM 128
#define HD     128
#define LMAX   5

#define NB_SCAN ((N_SUB + 255) / 256)   // 313
#define NBP 128   // prep grid (<=256 -> co-residency guaranteed)
#define NBT 128   // tail grid

// ---------------- grid barrier (device-scope) ----------------
// bar starts at 0 (memset per launch); phase ph = 1,2,3,... monotonically.

__device__ __forceinline__ void gbar(int* bar, int nblk, int ph) {
    __syncthreads();
    if (threadIdx.x == 0) {
        __threadfence();                       // release our writes (agent scope)
        atomicAdd(bar, 1);
        int target = nblk * ph;
        while (__hip_atomic_load(bar, __ATOMIC_ACQUIRE, __HIP_MEMORY_SCOPE_AGENT) < target) {
            __builtin_amdgcn_s_sleep(1);
        }
    }
    __syncthreads();
}

// ---------------- shared device functions ----------------

__device__ void dev_aggregate(
    const float* __restrict__ H, float* __restrict__ Out,
    const int* __restrict__ offs, const int* __restrict__ csr,
    const int* __restrict__ cnt, const int* __restrict__ order,
    int M, const int* __restrict__ srcmap, int bid0, int nb) {
    int ngroups = (M + 3) >> 2;
    int wid = threadIdx.x >> 6, lane = threadIdx.x & 63;
    for (int g = bid0; g < ngroups; g += nb) {
        int ni = g * 4 + wid;
        if (ni >= M) continue;
        int node = order[ni];
        int beg = offs[node], end = offs[node + 1];
        float ax = 0.f, ay = 0.f, bx = 0.f, by = 0.f;
        int j = beg;
        for (; j + 1 < end; j += 2) {
            int s0 = csr[j], s1 = csr[j + 1];
            int r0 = srcmap ? srcmap[s0] : s0;
            int r1 = srcmap ? srcmap[s1] : s1;
            float2 v0 = *(const float2*)(H + (size_t)r0 * HD + lane * 2);
            float2 v1 = *(const float2*)(H + (size_t)r1 * HD + lane * 2);
            ax += v0.x; ay += v0.y;
            bx += v1.x; by += v1.y;
        }
        if (j < end) {
            int s0 = csr[j];
            int r0 = srcmap ? srcmap[s0] : s0;
            float2 v0 = *(const float2*)(H + (size_t)r0 * HD + lane * 2);
            ax += v0.x; ay += v0.y;
        }
        int c = cnt[node];
        float inv = 1.0f / (float)(c > 1 ? c : 1);
        *(float2*)(Out + (size_t)node * HD + lane * 2) =
            make_float2((ax + bx) * inv, (ay + by) * inv);
    }
}

#define GBM 64
#define GBK 32

__device__ void dev_gemm(
    const float* __restrict__ A1, const float* __restrict__ A2,
    const float* __restrict__ W1, const float* __restrict__ W2,
    const float* __restrict__ bias, float* __restrict__ Out,
    const int* __restrict__ order, const int* __restrict__ gatherA,
    const int* __restrict__ gatherB, int M, int do_relu, int bid0, int nb) {

    __shared__ __align__(16) float As[GBK][68];
    __shared__ __align__(16) float Ws[GBK][132];

    int ntiles = (M + GBM - 1) / GBM;
    int tid = threadIdx.x;
    int tx = tid & 15, ty = tid >> 4;
    int r0 = ty * 4;
    int c0 = tx * 4;
    int nchunk = A2 ? 8 : 4;

    for (int tile = bid0; tile < ntiles; tile += nb) {
        int row0 = tile * GBM;

        float acc[4][8];
#pragma unroll
        for (int i = 0; i < 4; ++i)
#pragma unroll
            for (int j = 0; j < 8; ++j) acc[i][j] = 0.f;

        for (int ch = 0; ch < nchunk; ++ch) {
            const float* Asrc = (ch < 4) ? A1 : A2;
            const float* Wsrc = (ch < 4) ? W1 : W2;
            const int* gmap = (ch < 4) ? gatherA : gatherB;
            int kbase = (ch & 3) * GBK;

#pragma unroll
            for (int it = 0; it < 2; ++it) {
                int idx = tid + it * 256;
                int m = idx >> 3, kq = idx & 7;
                int row = row0 + m;
                float4 v = make_float4(0.f, 0.f, 0.f, 0.f);
                if (row < M) {
                    int nr = order[row];
                    int ar = gmap ? gmap[nr] : nr;
                    v = *(const float4*)(Asrc + (size_t)ar * 128 + kbase + kq * 4);
                }
                As[kq * 4 + 0][m] = v.x;
                As[kq * 4 + 1][m] = v.y;
                As[kq * 4 + 2][m] = v.z;
                As[kq * 4 + 3][m] = v.w;
            }
#pragma unroll
            for (int it = 0; it < 4; ++it) {
                int idx = tid + it * 256;
                int n = idx >> 3, kq = idx & 7;
                float4 v = *(const float4*)(Wsrc + n * 128 + kbase + kq * 4);
                Ws[kq * 4 + 0][n] = v.x;
                Ws[kq * 4 + 1][n] = v.y;
                Ws[kq * 4 + 2][n] = v.z;
                Ws[kq * 4 + 3][n] = v.w;
            }
            __syncthreads();

#pragma unroll
            for (int kk = 0; kk < GBK; ++kk) {
                float4 a  = *(const float4*)&As[kk][r0];
                float4 w0 = *(const float4*)&Ws[kk][c0];
                float4 w1 = *(const float4*)&Ws[kk][c0 + 64];
                float av[4] = {a.x, a.y, a.z, a.w};
                float wv[8] = {w0.x, w0.y, w0.z, w0.w, w1.x, w1.y, w1.z, w1.w};
#pragma unroll
                for (int i = 0; i < 4; ++i)
#pragma unroll
                    for (int j = 0; j < 8; ++j)
                        acc[i][j] = fmaf(av[i], wv[j], acc[i][j]);
            }
            __syncthreads();
        }

#pragma unroll
        for (int i = 0; i < 4; ++i) {
            int row = row0 + r0 + i;
            if (row >= M) continue;
            int nr = order[row];
            float4 o0, o1;
            o0.x = acc[i][0] + bias[c0 + 0];
            o0.y = acc[i][1] + bias[c0 + 1];
            o0.z = acc[i][2] + bias[c0 + 2];
            o0.w = acc[i][3] + bias[c0 + 3];
            o1.x = acc[i][4] + bias[c0 + 64];
            o1.y = acc[i][5] + bias[c0 + 65];
            o1.z = acc[i][6] + bias[c0 + 66];
            o1.w = acc[i][7] + bias[c0 + 67];
            if (do_relu) {
                o0.x = fmaxf(o0.x, 0.f); o0.y = fmaxf(o0.y, 0.f);
                o0.z = fmaxf(o0.z, 0.f); o0.w = fmaxf(o0.w, 0.f);
                o1.x = fmaxf(o1.x, 0.f); o1.y = fmaxf(o1.y, 0.f);
                o1.z = fmaxf(o1.z, 0.f); o1.w = fmaxf(o1.w, 0.f);
            }
            *(float4*)(Out + (size_t)nr * 128 + c0) = o0;
            *(float4*)(Out + (size_t)nr * 128 + c0 + 64) = o1;
        }
    }
}

__device__ void dev_head(
    const float* __restrict__ H,
    const float* __restrict__ W_e1, const float* __restrict__ b_e1,
    const float* __restrict__ W_e2, const float* __restrict__ b_e2,
    const float* __restrict__ W_h1, const float* __restrict__ b_h1,
    const float* __restrict__ W_h2, const float* __restrict__ b_h2,
    float* __restrict__ head_out, int kidx) {

    __shared__ float feat[384];
    __shared__ float rowo[128];
    __shared__ float sc_sh;
    int t = threadIdx.x, lane = t & 63, wv = t >> 6;

    if (t < 128) {
        float a = H[t], b = H[128 + t];
        feat[t] = a;
        feat[128 + t] = b;
        feat[256 + t] = a * b;
    }
    __syncthreads();

    for (int r = wv; r < 128; r += 4) {
        const float* wr = W_e1 + r * 384;
        float acc = 0.f;
#pragma unroll
        for (int j = 0; j < 6; ++j)
            acc += feat[lane + 64 * j] * wr[lane + 64 * j];
        for (int off = 32; off; off >>= 1) acc += __shfl_down(acc, off);
        if (lane == 0) rowo[r] = fmaxf(acc + b_e1[r], 0.f) * W_e2[r];
    }
    __syncthreads();
    if (wv == 0) {
        float v = rowo[lane] + rowo[lane + 64];
        for (int off = 32; off; off >>= 1) v += __shfl_down(v, off);
        if (lane == 0) sc_sh = v + b_e2[0];
    }
    __syncthreads();
    float score = sc_sh;

    for (int r = wv; r < 64; r += 4) {
        const float* wh = W_h1 + r * 257;
        float acc = 0.f;
#pragma unroll
        for (int j = 0; j < 4; ++j)
            acc += feat[lane + 64 * j] * wh[lane + 64 * j];
        if (lane == 0) acc += score * wh[256];
        for (int off = 32; off; off >>= 1) acc += __shfl_down(acc, off);
        if (lane == 0) rowo[r] = fmaxf(acc + b_h1[r], 0.f) * W_h2[r];
    }
    __syncthreads();
    if (wv == 0) {
        float v = rowo[lane];
        for (int off = 32; off; off >>= 1) v += __shfl_down(v, off);
        if (lane == 0) {
            float p = 1.f / (1.f + expf(-(v + b_h2[0])));
            head_out[kidx * 2 + 0] = score;
            head_out[kidx * 2 + 1] = p;
        }
    }
    __syncthreads();
}

// ---------------- prep: everything up to (and incl.) level compaction ----------------

__global__ __launch_bounds__(256) void prep_fused(
    const int* __restrict__ esrc, const int* __restrict__ edst,
    const float* __restrict__ W_l, const float* __restrict__ W_r,
    const float* __restrict__ W_in, const float* __restrict__ b_in,
    const float* __restrict__ b_l,
    int* __restrict__ cnt, int* __restrict__ cursor, int* __restrict__ level,
    int* __restrict__ offs, int* __restrict__ csr,
    int* __restrict__ bsums, int* __restrict__ bhist,
    int* __restrict__ lvlbase, int* __restrict__ cum, int* __restrict__ order,
    float* __restrict__ Wc1, float* __restrict__ Wc2, float* __restrict__ bc,
    int* __restrict__ bar) {

    __shared__ int si[256];
    __shared__ float sf[256];
    __shared__ int h8[8];
    __shared__ int tot8[8];
    __shared__ int woff[4][8];

    int t = threadIdx.x;
    int bid = blockIdx.x;
    int nb = gridDim.x;
    int gsz = nb * 256;
    int gi0 = bid * 256 + t;
    int ph = 0;

    // P0: init
    for (int i = gi0; i < N_SUB; i += gsz) {
        cnt[i] = 0; cursor[i] = 0; level[i] = (i < 2) ? 0 : 7;
    }
    gbar(bar, nb, ++ph);

    // P1: in-degree count
    for (int i = gi0; i < E_NUM; i += gsz)
        atomicAdd(&cnt[edst[i]], 1);
    gbar(bar, nb, ++ph);

    // P2: per-256-chunk exclusive scan
    for (int job = bid; job < NB_SCAN; job += nb) {
        int i = job * 256 + t;
        int v = (i < N_SUB) ? cnt[i] : 0;
        si[t] = v;
        __syncthreads();
        for (int off = 1; off < 256; off <<= 1) {
            int x = (t >= off) ? si[t - off] : 0;
            __syncthreads();
            si[t] += x;
            __syncthreads();
        }
        if (i < N_SUB) offs[i] = si[t] - v;
        if (t == 255) bsums[job] = si[255];
        __syncthreads();
    }
    gbar(bar, nb, ++ph);

    // P3: scan 313 block sums (block 0, wave 0, chunked wave-scan)
    if (bid == 0 && t < 64) {
        int lane = t;
        int base = 0;
        for (int c = 0; c < NB_SCAN; c += 64) {
            int idx = c + lane;
            int v0 = (idx < NB_SCAN) ? bsums[idx] : 0;
            int v = v0;
            for (int off = 1; off < 64; off <<= 1) {
                int x = __shfl_up(v, off);
                if (lane >= off) v += x;
            }
            if (idx < NB_SCAN) bsums[idx] = base + v - v0;
            base += __shfl(v, 63);
        }
    }
    gbar(bar, nb, ++ph);

    // P4: add block bases
    for (int i = gi0; i < N_SUB; i += gsz) offs[i] += bsums[i >> 8];
    if (gi0 == 0) offs[N_SUB] = E_NUM;
    gbar(bar, nb, ++ph);

    // P5: fill CSR
    for (int i = gi0; i < E_NUM; i += gsz) {
        int d = edst[i];
        int p = atomicAdd(&cursor[d], 1);
        csr[offs[d] + p] = esrc[i];
    }
    gbar(bar, nb, ++ph);

    // P6..P9: reverse BFS levels 1..4 (frontier-sparse via CSR)
    for (int tt = 0; tt < 4; ++tt) {
        for (int i = gi0; i < N_SUB; i += gsz) {
            if (level[i] == tt) {
                int beg = offs[i], end = offs[i + 1];
                for (int j = beg; j < end; ++j) {
                    int u = csr[j];
                    if (level[u] > tt + 1) level[u] = tt + 1;
                }
            }
        }
        gbar(bar, nb, ++ph);
    }

    // P10: per-chunk level histogram
    for (int job = bid; job < NB_SCAN; job += nb) {
        if (t < 8) h8[t] = 0;
        __syncthreads();
        int i = job * 256 + t;
        if (i < N_SUB) {
            int l = level[i];
            if (l > 5) l = 6;
            atomicAdd(&h8[l], 1);
        }
        __syncthreads();
        if (t < 8) bhist[job * 8 + t] = h8[t];
        __syncthreads();
    }
    gbar(bar, nb, ++ph);

    // P11: per-level scan of bhist + base/cum (block 0)
    if (bid == 0) {
        int wv = t >> 6, lane = t & 63;
        for (int l = wv; l < 8; l += 4) {
            int base = 0;
            for (int c = 0; c < NB_SCAN; c += 64) {
                int idx = c + lane;
                int v0 = (idx < NB_SCAN) ? bhist[idx * 8 + l] : 0;
                int v = v0;
                for (int off = 1; off < 64; off <<= 1) {
                    int x = __shfl_up(v, off);
                    if (lane >= off) v += x;
                }
                if (idx < NB_SCAN) bhist[idx * 8 + l] = base + v - v0;
                base += __shfl(v, 63);
            }
            if (lane == 0) tot8[l] = base;
        }
        __syncthreads();
        if (t == 0) {
            int acc = 0;
            for (int l = 0; l <= 5; ++l) {
                lvlbase[l] = acc;
                acc += tot8[l];
                cum[l] = acc;
            }
        }
    }
    gbar(bar, nb, ++ph);

    // P12: emit order (ballot-ranked, stable, atomic-free)
    {
        int lane = t & 63, wv = t >> 6;
        for (int job = bid; job < NB_SCAN; job += nb) {
            int i = job * 256 + t;
            int l = 7;
            if (i < N_SUB) {
                l = level[i];
                if (l > 5) l = 6;
            }
            unsigned long long mybal = 0;
#pragma unroll
            for (int q = 0; q < 8; ++q) {
                unsigned long long b = __ballot(l == q);
                if (q == l) mybal = b;
                if (lane == 0) woff[wv][q] = (int)__popcll(b);
            }
            int inrank = (int)__popcll(mybal & ((1ull << lane) - 1ull));
            __syncthreads();
            if (t < 8) {
                int acc = 0;
                for (int w2 = 0; w2 < 4; ++w2) {
                    int c = woff[w2][t];
                    woff[w2][t] = acc;
                    acc += c;
                }
            }
            __syncthreads();
            if (i < N_SUB && l <= 5) {
                int pos = lvlbase[l] + bhist[job * 8 + l] + woff[wv][l] + inrank;
                order[pos] = i;
            }
            __syncthreads();
        }
    }

    // P13: combined weights Wc1=W_l@W_in, Wc2=W_r@W_in, bc (independent of P12)
    for (int f = bid; f < 128; f += nb) {
        if (t < 128) sf[t] = W_l[f * 128 + t];
        else sf[t] = W_r[f * 128 + (t - 128)];
        __syncthreads();
        int c = t & 127, p = t >> 7;
        const float* wrow = p ? (sf + 128) : sf;
        float acc = 0.f;
#pragma unroll 8
        for (int j = 0; j < 128; ++j)
            acc = fmaf(wrow[j], W_in[j * 128 + c], acc);
        (p ? Wc2 : Wc1)[f * 128 + c] = acc;
        if (t < 64) {
            float pa = (sf[t] + sf[128 + t]) * b_in[t] +
                       (sf[t + 64] + sf[192 + t]) * b_in[t + 64];
            for (int off = 32; off; off >>= 1) pa += __shfl_down(pa, off);
            if (t == 0) bc[f] = pa + b_l[f];
        }
        __syncthreads();
    }
}

// ---------------- step-1 wrappers (large grids, no barriers) ----------------

__global__ __launch_bounds__(256) void aggregate_list(
    const float* __restrict__ H, float* __restrict__ Out,
    const int* __restrict__ offs, const int* __restrict__ csr,
    const int* __restrict__ cnt, const int* __restrict__ order,
    const int* __restrict__ cumptr, int lvl, const int* __restrict__ srcmap) {
    int M = cumptr[lvl];
    dev_aggregate(H, Out, offs, csr, cnt, order, M, srcmap, blockIdx.x, gridDim.x);
}

__global__ __launch_bounds__(256) void gemm_list(
    const float* __restrict__ A1, const float* __restrict__ A2,
    const float* __restrict__ W1, const float* __restrict__ W2,
    const float* __restrict__ bias, float* __restrict__ Out,
    const int* __restrict__ order, const int* __restrict__ gatherA,
    const int* __restrict__ gatherB, const int* __restrict__ cumptr,
    int lvl, int do_relu) {
    int M = cumptr[lvl];
    dev_gemm(A1, A2, W1, W2, bias, Out, order, gatherA, gatherB, M, do_relu,
             blockIdx.x, gridDim.x);
}

// ---------------- fused tail: steps 2..5 + heads + finalize ----------------

__global__ __launch_bounds__(256) void tail_fused(
    float* __restrict__ HA, float* __restrict__ HB,
    const int* __restrict__ offs, const int* __restrict__ csr,
    const int* __restrict__ cnt, const int* __restrict__ order,
    const int* __restrict__ cum,
    const float* __restrict__ W_l, const float* __restrict__ b_l,
    const float* __restrict__ W_r,
    const float* __restrict__ W_e1, const float* __restrict__ b_e1,
    const float* __restrict__ W_e2, const float* __restrict__ b_e2,
    const float* __restrict__ W_h1, const float* __restrict__ b_h1,
    const float* __restrict__ W_h2, const float* __restrict__ b_h2,
    float* __restrict__ head_out, float* __restrict__ out,
    int* __restrict__ bar) {

    int bid = blockIdx.x, nb = gridDim.x;
    int ph = 0;

    // head for k=1 (H1 already in HA from step-1 dispatches)
    if (bid == 0)
        dev_head(HA, W_e1, b_e1, W_e2, b_e2, W_h1, b_h1, W_h2, b_h2, head_out, 0);
    gbar(bar, nb, ++ph);

    for (int k = 2; k <= LMAX; ++k) {
        int lvl = LMAX - k;
        int M = cum[lvl];
        dev_aggregate(HA, HB, offs, csr, cnt, order, M, nullptr, bid, nb);
        gbar(bar, nb, ++ph);
        dev_gemm(HB, HA, W_l, W_r, b_l, HA, order, nullptr, nullptr, M, 1, bid, nb);
        gbar(bar, nb, ++ph);
        if (bid == 0)
            dev_head(HA, W_e1, b_e1, W_e2, b_e2, W_h1, b_h1, W_h2, b_h2,
                     head_out, k - 1);
        if (k < LMAX) gbar(bar, nb, ++ph);
    }

    // finalize (block 0, thread 0; all head_out written by this same thread)
    if (bid == 0 && threadIdx.x == 0) {
        float a[LMAX];
        float p_not = 1.f, s = 0.f;
        for (int k = 0; k < LMAX; ++k) {
            float p = head_out[2 * k + 1];
            a[k] = p * p_not;
            p_not *= (1.f - p);
            s += a[k];
        }
        float inv = 1.f / (s + 1e-8f);
        float fs = 0.f, ed = 0.f;
        for (int k = 0; k < LMAX; ++k) {
            float al = a[k] * inv;
            out[2 + k] = al;
            fs += al * head_out[2 * k];
            ed += al * (float)(k + 1);
        }
        out[0] = fs;
        out[1] = ed;
    }
}

// ---------------- launch ----------------

extern "C" void kernel_launch(void* const* d_in, const int* in_sizes, int n_in,
                              void* d_out, int out_size, void* d_ws, size_t ws_size,
                              hipStream_t stream) {
    const float* x_full = (const float*)d_in[0];
    const float* W_in  = (const float*)d_in[1];
    const float* b_in  = (const float*)d_in[2];
    const float* W_l   = (const float*)d_in[3];
    const float* b_l   = (const float*)d_in[4];
    const float* W_r   = (const float*)d_in[5];
    const float* W_e1  = (const float*)d_in[6];
    const float* b_e1  = (const float*)d_in[7];
    const float* W_e2  = (const float*)d_in[8];
    const float* b_e2  = (const float*)d_in[9];
    const float* W_h1  = (const float*)d_in[10];
    const float* b_h1  = (const float*)d_in[11];
    const float* W_h2  = (const float*)d_in[12];
    const float* b_h2  = (const float*)d_in[13];
    const int* subset  = (const int*)d_in[14];
    const int* edge    = (const int*)d_in[15];
    const int* esrc = edge;
    const int* edst = edge + E_NUM;

    // workspace carve-up
    char* w = (char*)d_ws;
    float* HA = (float*)w;      w += (size_t)N_SUB * HD * 4;
    float* HB = (float*)w;      w += (size_t)N_SUB * HD * 4;
    int* cnt = (int*)w;         w += (size_t)N_SUB * 4;
    int* offs = (int*)w;        w += (size_t)(N_SUB + 64) * 4;
    int* cursor = (int*)w;      w += (size_t)N_SUB * 4;
    int* csr = (int*)w;         w += (size_t)E_NUM * 4;
    int* level = (int*)w;       w += (size_t)N_SUB * 4;
    int* order = (int*)w;       w += (size_t)N_SUB * 4;
    int* bsums = (int*)w;       w += 4096;
    int* bhist = (int*)w;       w += (size_t)(NB_SCAN + 1) * 8 * 4;
    int* lvlbase = (int*)w;     w += 64;
    int* cum = (int*)w;         w += 64;
    float* Wc1 = (float*)w;     w += 128 * 128 * 4;
    float* Wc2 = (float*)w;     w += 128 * 128 * 4;
    float* bc = (float*)w;      w += 512;
    float* head_out = (float*)w; w += 256;
    int* bars = (int*)w;        w += 256;   // bars[0]=prep, bars[16]=tail

    hipMemsetAsync(bars, 0, 256, stream);

    prep_fused<<<NBP, 256, 0, stream>>>(
        esrc, edst, W_l, W_r, W_in, b_in, b_l,
        cnt, cursor, level, offs, csr, bsums, bhist, lvlbase, cum, order,
        Wc1, Wc2, bc, bars);

    // step 1 on C_4 via linearity of the input projection
    aggregate_list<<<2048, 256, 0, stream>>>(
        x_full, HB, offs, csr, cnt, order, cum, 4, subset);
    gemm_list<<<512, 256, 0, stream>>>(
        HB, x_full, Wc1, Wc2, bc, HA, order, nullptr, subset, cum, 4, 1);

    tail_fused<<<NBT, 256, 0, stream>>>(
        HA, HB, offs, csr, cnt, order, cum,
        W_l, b_l, W_r, W_e1, b_e1, W_e2, b_e2, W_h1, b_h1, W_h2, b_h2,
        head_out, (float*)d_out, bars + 16);
}

// Round 6
// 721.108 us; speedup vs baseline: 1.1868x; 1.1868x over previous
//
#include <hip/hip_runtime.h>
#include <hip/hip_bf16.h>

#define N_FULL 200000
#define N_SUB  80000
#define E_NUM  800000
#define IN_DIM 128
#define HD     128
#define LMAX   5

#define NB_E (E_NUM / 256)          // 3125
#define WCOMB_BLKS 128

// ---------------- count in-degree ----------------

__global__ void count_deg(const int* __restrict__ dst, int* __restrict__ cnt) {
    int i = blockIdx.x * blockDim.x + threadIdx.x;
    if (i < E_NUM) atomicAdd(&cnt[dst[i]], 1);
}

// ---------------- single-block scan (cnt -> offs) + level init ----------------

__global__ __launch_bounds__(1024) void scan_plus(const int* __restrict__ cnt,
                                                  int* __restrict__ offs,
                                                  int* __restrict__ level) {
    __shared__ int wsum[16];
    int t = threadIdx.x, lane = t & 63, wv = t >> 6;
    int carry = 0;
    const int NCH = (N_SUB + 1023) / 1024;   // 79
    for (int c = 0; c < NCH; ++c) {
        int i = c * 1024 + t;
        int v = (i < N_SUB) ? cnt[i] : 0;
        int x = v;
#pragma unroll
        for (int off = 1; off < 64; off <<= 1) {
            int y = __shfl_up(x, off);
            if (lane >= off) x += y;
        }
        if (lane == 63) wsum[wv] = x;
        __syncthreads();
        int wbase = 0, total = 0;
#pragma unroll
        for (int w2 = 0; w2 < 16; ++w2) {
            int s = wsum[w2];
            if (w2 < wv) wbase += s;
            total += s;
        }
        if (i < N_SUB) {
            offs[i] = carry + wbase + x - v;
            level[i] = (i < 2) ? 0 : 7;
        }
        carry += total;
        __syncthreads();
    }
    if (t == 0) offs[N_SUB] = E_NUM;
}

// ---------------- fill CSR (atomicSub on degree) + wcomb in spare blocks ----------------
// Wc1 = W_l@W_in, Wc2 = W_r@W_in, bc = (W_l+W_r)@b_in + b_l

__global__ __launch_bounds__(256) void fill_wcomb(
    const int* __restrict__ esrc, const int* __restrict__ edst,
    const int* __restrict__ offs, int* __restrict__ cnt, int* __restrict__ csr,
    const float* __restrict__ W_l, const float* __restrict__ W_r,
    const float* __restrict__ W_in, const float* __restrict__ b_in,
    const float* __restrict__ b_l,
    float* __restrict__ Wc1, float* __restrict__ Wc2, float* __restrict__ bc) {
    int b = blockIdx.x;
    int t = threadIdx.x;
    if (b < NB_E) {
        int i = b * 256 + t;
        int d = edst[i];
        int p = atomicSub(&cnt[d], 1) - 1;   // unique slot in [0, deg)
        csr[offs[d] + p] = esrc[i];
    } else {
        __shared__ float sf[256];
        int f = b - NB_E;                    // 0..127
        if (t < 128) sf[t] = W_l[f * 128 + t];
        else sf[t] = W_r[f * 128 + (t - 128)];
        __syncthreads();
        int c = t & 127, p = t >> 7;
        const float* wrow = p ? (sf + 128) : sf;
        float acc = 0.f;
#pragma unroll 8
        for (int j = 0; j < 128; ++j)
            acc = fmaf(wrow[j], W_in[j * 128 + c], acc);
        (p ? Wc2 : Wc1)[f * 128 + c] = acc;
        if (t < 64) {
            float pa = (sf[t] + sf[128 + t]) * b_in[t] +
                       (sf[t + 64] + sf[192 + t]) * b_in[t + 64];
            for (int off = 32; off; off >>= 1) pa += __shfl_down(pa, off);
            if (t == 0) bc[f] = pa + b_l[f];
        }
    }
}

// ---------------- single-block frontier BFS + level-grouped compaction ----------------
// order[] = nodes grouped by BFS level from {0,1}; cum[t] = #nodes with level<=t.

__global__ __launch_bounds__(1024) void bfs_compact(
    const int* __restrict__ offs, const int* __restrict__ csr,
    int* __restrict__ level, int* __restrict__ order, int* __restrict__ cum) {
    __shared__ int qtail_s, qcnt;
    int t = threadIdx.x;
    if (t == 0) { order[0] = 0; order[1] = 1; qtail_s = 2; qcnt = 0; cum[0] = 2; }
    __syncthreads();
    int qhead = 0, qtail = 2;
    for (int lvl = 0; lvl < 4; ++lvl) {
        for (int idx = qhead + t; idx < qtail; idx += 1024) {
            int v = order[idx];
            int beg = offs[v], end = offs[v + 1];
            for (int j = beg; j < end; ++j) {
                int u = csr[j];
                if (level[u] == 7) {
                    if (atomicMin(&level[u], lvl + 1) == 7) {
                        int p = atomicAdd(&qcnt, 1);
                        order[qtail + p] = u;
                    }
                }
            }
        }
        __syncthreads();
        if (t == 0) { qtail_s = qtail + qcnt; qcnt = 0; cum[lvl + 1] = qtail_s; }
        __syncthreads();
        qhead = qtail;
        qtail = qtail_s;
        __syncthreads();
    }
}

// ---------------- head MLP on nodes 0,1 (device fn, 256 threads) ----------------

__device__ void dev_head(
    const float* __restrict__ H,
    const float* __restrict__ W_e1, const float* __restrict__ b_e1,
    const float* __restrict__ W_e2, const float* __restrict__ b_e2,
    const float* __restrict__ W_h1, const float* __restrict__ b_h1,
    const float* __restrict__ W_h2, const float* __restrict__ b_h2,
    float* __restrict__ head_out, int kidx) {

    __shared__ float feat[384];
    __shared__ float rowo[128];
    __shared__ float sc_sh;
    int t = threadIdx.x, lane = t & 63, wv = t >> 6;

    __syncthreads();
    if (t < 128) {
        float a = H[t], b = H[128 + t];
        feat[t] = a;
        feat[128 + t] = b;
        feat[256 + t] = a * b;
    }
    __syncthreads();

    for (int r = wv; r < 128; r += 4) {
        const float* wr = W_e1 + r * 384;
        float acc = 0.f;
#pragma unroll
        for (int j = 0; j < 6; ++j)
            acc += feat[lane + 64 * j] * wr[lane + 64 * j];
        for (int off = 32; off; off >>= 1) acc += __shfl_down(acc, off);
        if (lane == 0) rowo[r] = fmaxf(acc + b_e1[r], 0.f) * W_e2[r];
    }
    __syncthreads();
    if (wv == 0) {
        float v = rowo[lane] + rowo[lane + 64];
        for (int off = 32; off; off >>= 1) v += __shfl_down(v, off);
        if (lane == 0) sc_sh = v + b_e2[0];
    }
    __syncthreads();
    float score = sc_sh;

    for (int r = wv; r < 64; r += 4) {
        const float* wh = W_h1 + r * 257;
        float acc = 0.f;
#pragma unroll
        for (int j = 0; j < 4; ++j)
            acc += feat[lane + 64 * j] * wh[lane + 64 * j];
        if (lane == 0) acc += score * wh[256];
        for (int off = 32; off; off >>= 1) acc += __shfl_down(acc, off);
        if (lane == 0) rowo[r] = fmaxf(acc + b_h1[r], 0.f) * W_h2[r];
    }
    __syncthreads();
    if (wv == 0) {
        float v = rowo[lane];
        for (int off = 32; off; off >>= 1) v += __shfl_down(v, off);
        if (lane == 0) {
            float p = 1.f / (1.f + expf(-(v + b_h2[0])));
            head_out[kidx * 2 + 0] = score;
            head_out[kidx * 2 + 1] = p;
        }
    }
    __syncthreads();
}

// ---------------- fused agg+GEMM (+optional head), 256 threads ----------------
// rows i < M: nr = order[i]
//   A1-operand (ch<4): mean over in-neighbors u of nr of A1[map(u)][:]
//   A2-operand (ch>=4): A2[map(nr)][:]
// Out[nr][:] = relu( agg @ W1.T + direct @ W2.T + bias )

#define GBM 64
#define GBK 32

__device__ void dev_gemm_fused(
    const float* __restrict__ A1, const float* __restrict__ A2,
    const float* __restrict__ W1, const float* __restrict__ W2,
    const float* __restrict__ bias, float* __restrict__ Out,
    const int* __restrict__ order, const int* __restrict__ offs,
    const int* __restrict__ csr, const int* __restrict__ srcmap,
    int M, int bid0, int nb,
    const float* __restrict__ W_e1, const float* __restrict__ b_e1,
    const float* __restrict__ W_e2, const float* __restrict__ b_e2,
    const float* __restrict__ W_h1, const float* __restrict__ b_h1,
    const float* __restrict__ W_h2, const float* __restrict__ b_h2,
    float* __restrict__ head_out, int head_kidx) {

    __shared__ __align__(16) float As[GBK][68];
    __shared__ __align__(16) float Ws[GBK][132];

    int ntiles = (M + GBM - 1) / GBM;
    int tid = threadIdx.x;
    int tx = tid & 15, ty = tid >> 4;
    int r0 = ty * 4;
    int c0 = tx * 4;

    for (int tile = bid0; tile < ntiles; tile += nb) {
        int row0 = tile * GBM;

        float acc[4][8];
#pragma unroll
        for (int i = 0; i < 4; ++i)
#pragma unroll
            for (int j = 0; j < 8; ++j) acc[i][j] = 0.f;

        for (int ch = 0; ch < 8; ++ch) {
            const float* Wsrc = (ch < 4) ? W1 : W2;
            int kbase = (ch & 3) * GBK;

            // stage A tile (64 rows x 32 k) transposed into As[k][m]
#pragma unroll
            for (int it = 0; it < 2; ++it) {
                int idx = tid + it * 256;
                int m = idx >> 3, kq = idx & 7;
                int row = row0 + m;
                float4 v = make_float4(0.f, 0.f, 0.f, 0.f);
                if (row < M) {
                    int nr = order[row];
                    if (ch < 4) {
                        int beg = offs[nr], end = offs[nr + 1];
                        for (int j = beg; j < end; ++j) {
                            int u = csr[j];
                            int ar = srcmap ? srcmap[u] : u;
                            float4 t4 = *(const float4*)(A1 + (size_t)ar * 128 + kbase + kq * 4);
                            v.x += t4.x; v.y += t4.y; v.z += t4.z; v.w += t4.w;
                        }
                        int deg = end - beg;
                        float inv = 1.0f / (float)(deg > 1 ? deg : 1);
                        v.x *= inv; v.y *= inv; v.z *= inv; v.w *= inv;
                    } else {
                        int ar = srcmap ? srcmap[nr] : nr;
                        v = *(const float4*)(A2 + (size_t)ar * 128 + kbase + kq * 4);
                    }
                }
                As[kq * 4 + 0][m] = v.x;
                As[kq * 4 + 1][m] = v.y;
                As[kq * 4 + 2][m] = v.z;
                As[kq * 4 + 3][m] = v.w;
            }
            // stage W tile (128 n x 32 k) transposed into Ws[k][n]
#pragma unroll
            for (int it = 0; it < 4; ++it) {
                int idx = tid + it * 256;
                int n = idx >> 3, kq = idx & 7;
                float4 v = *(const float4*)(Wsrc + n * 128 + kbase + kq * 4);
                Ws[kq * 4 + 0][n] = v.x;
                Ws[kq * 4 + 1][n] = v.y;
                Ws[kq * 4 + 2][n] = v.z;
                Ws[kq * 4 + 3][n] = v.w;
            }
            __syncthreads();

#pragma unroll
            for (int kk = 0; kk < GBK; ++kk) {
                float4 a  = *(const float4*)&As[kk][r0];
                float4 w0 = *(const float4*)&Ws[kk][c0];
                float4 w1 = *(const float4*)&Ws[kk][c0 + 64];
                float av[4] = {a.x, a.y, a.z, a.w};
                float wv[8] = {w0.x, w0.y, w0.z, w0.w, w1.x, w1.y, w1.z, w1.w};
#pragma unroll
                for (int i = 0; i < 4; ++i)
#pragma unroll
                    for (int j = 0; j < 8; ++j)
                        acc[i][j] = fmaf(av[i], wv[j], acc[i][j]);
            }
            __syncthreads();
        }

        // epilogue (relu always)
#pragma unroll
        for (int i = 0; i < 4; ++i) {
            int row = row0 + r0 + i;
            if (row >= M) continue;
            int nr = order[row];
            float4 o0, o1;
            o0.x = fmaxf(acc[i][0] + bias[c0 + 0], 0.f);
            o0.y = fmaxf(acc[i][1] + bias[c0 + 1], 0.f);
            o0.z = fmaxf(acc[i][2] + bias[c0 + 2], 0.f);
            o0.w = fmaxf(acc[i][3] + bias[c0 + 3], 0.f);
            o1.x = fmaxf(acc[i][4] + bias[c0 + 64], 0.f);
            o1.y = fmaxf(acc[i][5] + bias[c0 + 65], 0.f);
            o1.z = fmaxf(acc[i][6] + bias[c0 + 66], 0.f);
            o1.w = fmaxf(acc[i][7] + bias[c0 + 67], 0.f);
            *(float4*)(Out + (size_t)nr * 128 + c0) = o0;
            *(float4*)(Out + (size_t)nr * 128 + c0 + 64) = o1;
        }

        // fused head: tile 0 computed rows 0,1 (= nodes 0,1) fully
        if (tile == 0 && head_kidx >= 0) {
            dev_head(Out, W_e1, b_e1, W_e2, b_e2, W_h1, b_h1, W_h2, b_h2,
                     head_out, head_kidx);
        }
    }
}

__global__ __launch_bounds__(256) void gemm_fused(
    const float* __restrict__ A1, const float* __restrict__ A2,
    const float* __restrict__ W1, const float* __restrict__ W2,
    const float* __restrict__ bias, float* __restrict__ Out,
    const int* __restrict__ order, const int* __restrict__ offs,
    const int* __restrict__ csr, const int* __restrict__ srcmap,
    const int* __restrict__ cum, int lvl,
    const float* __restrict__ W_e1, const float* __restrict__ b_e1,
    const float* __restrict__ W_e2, const float* __restrict__ b_e2,
    const float* __restrict__ W_h1, const float* __restrict__ b_h1,
    const float* __restrict__ W_h2, const float* __restrict__ b_h2,
    float* __restrict__ head_out, int head_kidx) {
    int M = cum[lvl];
    dev_gemm_fused(A1, A2, W1, W2, bias, Out, order, offs, csr, srcmap, M,
                   blockIdx.x, gridDim.x,
                   W_e1, b_e1, W_e2, b_e2, W_h1, b_h1, W_h2, b_h2,
                   head_out, head_kidx);
}

// ---------------- tail: steps 4,5 + heads + finalize (one block) ----------------

__global__ __launch_bounds__(256) void tail_small(
    float* __restrict__ HA, float* __restrict__ HB,
    const int* __restrict__ order, const int* __restrict__ offs,
    const int* __restrict__ csr, const int* __restrict__ cum,
    const float* __restrict__ W_l, const float* __restrict__ b_l,
    const float* __restrict__ W_r,
    const float* __restrict__ W_e1, const float* __restrict__ b_e1,
    const float* __restrict__ W_e2, const float* __restrict__ b_e2,
    const float* __restrict__ W_h1, const float* __restrict__ b_h1,
    const float* __restrict__ W_h2, const float* __restrict__ b_h2,
    float* __restrict__ head_out, float* __restrict__ out) {

    // k=4 on C_1: HA -> HB, head kidx=3
    dev_gemm_fused(HA, HA, W_l, W_r, b_l, HB, order, offs, csr, nullptr,
                   cum[1], 0, 1,
                   W_e1, b_e1, W_e2, b_e2, W_h1, b_h1, W_h2, b_h2, head_out, 3);
    __syncthreads();
    // k=5 on C_0: HB -> HA, head kidx=4
    dev_gemm_fused(HB, HB, W_l, W_r, b_l, HA, order, offs, csr, nullptr,
                   cum[0], 0, 1,
                   W_e1, b_e1, W_e2, b_e2, W_h1, b_h1, W_h2, b_h2, head_out, 4);
    __syncthreads();

    if (threadIdx.x == 0) {
        float a[LMAX];
        float p_not = 1.f, s = 0.f;
        for (int k = 0; k < LMAX; ++k) {
            float p = head_out[2 * k + 1];
            a[k] = p * p_not;
            p_not *= (1.f - p);
            s += a[k];
        }
        float inv = 1.f / (s + 1e-8f);
        float fs = 0.f, ed = 0.f;
        for (int k = 0; k < LMAX; ++k) {
            float al = a[k] * inv;
            out[2 + k] = al;
            fs += al * head_out[2 * k];
            ed += al * (float)(k + 1);
        }
        out[0] = fs;
        out[1] = ed;
    }
}

// ---------------- launch ----------------

extern "C" void kernel_launch(void* const* d_in, const int* in_sizes, int n_in,
                              void* d_out, int out_size, void* d_ws, size_t ws_size,
                              hipStream_t stream) {
    const float* x_full = (const float*)d_in[0];
    const float* W_in  = (const float*)d_in[1];
    const float* b_in  = (const float*)d_in[2];
    const float* W_l   = (const float*)d_in[3];
    const float* b_l   = (const float*)d_in[4];
    const float* W_r   = (const float*)d_in[5];
    const float* W_e1  = (const float*)d_in[6];
    const float* b_e1  = (const float*)d_in[7];
    const float* W_e2  = (const float*)d_in[8];
    const float* b_e2  = (const float*)d_in[9];
    const float* W_h1  = (const float*)d_in[10];
    const float* b_h1  = (const float*)d_in[11];
    const float* W_h2  = (const float*)d_in[12];
    const float* b_h2  = (const float*)d_in[13];
    const int* subset  = (const int*)d_in[14];
    const int* edge    = (const int*)d_in[15];
    const int* esrc = edge;
    const int* edst = edge + E_NUM;

    // workspace carve-up
    char* w = (char*)d_ws;
    float* HA = (float*)w;      w += (size_t)N_SUB * HD * 4;
    float* HB = (float*)w;      w += (size_t)N_SUB * HD * 4;
    int* cnt = (int*)w;         w += (size_t)N_SUB * 4;
    int* offs = (int*)w;        w += (size_t)(N_SUB + 64) * 4;
    int* csr = (int*)w;         w += (size_t)E_NUM * 4;
    int* level = (int*)w;       w += (size_t)N_SUB * 4;
    int* order = (int*)w;       w += (size_t)N_SUB * 4;
    int* cum = (int*)w;         w += 64;
    float* Wc1 = (float*)w;     w += 128 * 128 * 4;
    float* Wc2 = (float*)w;     w += 128 * 128 * 4;
    float* bc = (float*)w;      w += 512;
    float* head_out = (float*)w; w += 256;

    hipMemsetAsync(cnt, 0, (size_t)N_SUB * 4, stream);
    count_deg<<<NB_E, 256, 0, stream>>>(edst, cnt);
    scan_plus<<<1, 1024, 0, stream>>>(cnt, offs, level);
    fill_wcomb<<<NB_E + WCOMB_BLKS, 256, 0, stream>>>(
        esrc, edst, offs, cnt, csr, W_l, W_r, W_in, b_in, b_l, Wc1, Wc2, bc);
    bfs_compact<<<1, 1024, 0, stream>>>(offs, csr, level, order, cum);

    // k=1 on C_4 (linearity: agg over raw x, combined weights)
    gemm_fused<<<512, 256, 0, stream>>>(
        x_full, x_full, Wc1, Wc2, bc, HA, order, offs, csr, subset, cum, 4,
        W_e1, b_e1, W_e2, b_e2, W_h1, b_h1, W_h2, b_h2, head_out, 0);
    // k=2 on C_3: HA -> HB
    gemm_fused<<<128, 256, 0, stream>>>(
        HA, HA, W_l, W_r, b_l, HB, order, offs, csr, nullptr, cum, 3,
        W_e1, b_e1, W_e2, b_e2, W_h1, b_h1, W_h2, b_h2, head_out, 1);
    // k=3 on C_2: HB -> HA
    gemm_fused<<<32, 256, 0, stream>>>(
        HB, HB, W_l, W_r, b_l, HA, order, offs, csr, nullptr, cum, 2,
        W_e1, b_e1, W_e2, b_e2, W_h1, b_h1, W_h2, b_h2, head_out, 2);
    // k=4,5 + finalize
    tail_small<<<1, 256, 0, stream>>>(
        HA, HB, order, offs, csr, cum,
        W_l, b_l, W_r, W_e1, b_e1, W_e2, b_e2, W_h1, b_h1, W_h2, b_h2,
        head_out, (float*)d_out);
}

// Round 7
// 610.509 us; speedup vs baseline: 1.4018x; 1.1812x over previous
//
#include <hip/hip_runtime.h>
#include <hip/hip_bf16.h>

#define N_FULL 200000
#define N_SUB  80000
#define E_NUM  800000
#define IN_DIM 128
#define HD     128
#define LMAX   5

#define NB_E (E_NUM / 256)          // 3125
#define WCOMB_BLKS 128

// ---------------- count in-degree ----------------

__global__ void count_deg(const int* __restrict__ dst, int* __restrict__ cnt) {
    int i = blockIdx.x * blockDim.x + threadIdx.x;
    if (i < E_NUM) atomicAdd(&cnt[dst[i]], 1);
}

// ---------------- single-block scan (cnt -> offs) + level init ----------------

__global__ __launch_bounds__(1024) void scan_plus(const int* __restrict__ cnt,
                                                  int* __restrict__ offs,
                                                  int* __restrict__ level) {
    __shared__ int wsum[16];
    int t = threadIdx.x, lane = t & 63, wv = t >> 6;
    int carry = 0;
    const int NCH = (N_SUB + 1023) / 1024;   // 79
    for (int c = 0; c < NCH; ++c) {
        int i = c * 1024 + t;
        int v = (i < N_SUB) ? cnt[i] : 0;
        int x = v;
#pragma unroll
        for (int off = 1; off < 64; off <<= 1) {
            int y = __shfl_up(x, off);
            if (lane >= off) x += y;
        }
        if (lane == 63) wsum[wv] = x;
        __syncthreads();
        int wbase = 0, total = 0;
#pragma unroll
        for (int w2 = 0; w2 < 16; ++w2) {
            int s = wsum[w2];
            if (w2 < wv) wbase += s;
            total += s;
        }
        if (i < N_SUB) {
            offs[i] = carry + wbase + x - v;
            level[i] = (i < 2) ? 0 : 7;
        }
        carry += total;
        __syncthreads();
    }
    if (t == 0) offs[N_SUB] = E_NUM;
}

// ---------------- fill CSR (atomicSub on degree) + wcomb in spare blocks ----------------

__global__ __launch_bounds__(256) void fill_wcomb(
    const int* __restrict__ esrc, const int* __restrict__ edst,
    const int* __restrict__ offs, int* __restrict__ cnt, int* __restrict__ csr,
    const float* __restrict__ W_l, const float* __restrict__ W_r,
    const float* __restrict__ W_in, const float* __restrict__ b_in,
    const float* __restrict__ b_l,
    float* __restrict__ Wc1, float* __restrict__ Wc2, float* __restrict__ bc) {
    int b = blockIdx.x;
    int t = threadIdx.x;
    if (b < NB_E) {
        int i = b * 256 + t;
        int d = edst[i];
        int p = atomicSub(&cnt[d], 1) - 1;   // unique slot in [0, deg)
        csr[offs[d] + p] = esrc[i];
    } else {
        __shared__ float sf[256];
        int f = b - NB_E;                    // 0..127
        if (t < 128) sf[t] = W_l[f * 128 + t];
        else sf[t] = W_r[f * 128 + (t - 128)];
        __syncthreads();
        int c = t & 127, p = t >> 7;
        const float* wrow = p ? (sf + 128) : sf;
        float acc = 0.f;
#pragma unroll 8
        for (int j = 0; j < 128; ++j)
            acc = fmaf(wrow[j], W_in[j * 128 + c], acc);
        (p ? Wc2 : Wc1)[f * 128 + c] = acc;
        if (t < 64) {
            float pa = (sf[t] + sf[128 + t]) * b_in[t] +
                       (sf[t + 64] + sf[192 + t]) * b_in[t + 64];
            for (int off = 32; off; off >>= 1) pa += __shfl_down(pa, off);
            if (t == 0) bc[f] = pa + b_l[f];
        }
    }
}

// ---------------- single-block frontier BFS + level-grouped compaction ----------------

__global__ __launch_bounds__(1024) void bfs_compact(
    const int* __restrict__ offs, const int* __restrict__ csr,
    int* __restrict__ level, int* __restrict__ order, int* __restrict__ cum) {
    __shared__ int qtail_s, qcnt;
    int t = threadIdx.x;
    if (t == 0) { order[0] = 0; order[1] = 1; qtail_s = 2; qcnt = 0; cum[0] = 2; }
    __syncthreads();
    int qhead = 0, qtail = 2;
    for (int lvl = 0; lvl < 4; ++lvl) {
        for (int idx = qhead + t; idx < qtail; idx += 1024) {
            int v = order[idx];
            int beg = offs[v], end = offs[v + 1];
            for (int j = beg; j < end; ++j) {
                int u = csr[j];
                if (level[u] == 7) {
                    if (atomicMin(&level[u], lvl + 1) == 7) {
                        int p = atomicAdd(&qcnt, 1);
                        order[qtail + p] = u;
                    }
                }
            }
        }
        __syncthreads();
        if (t == 0) { qtail_s = qtail + qcnt; qcnt = 0; cum[lvl + 1] = qtail_s; }
        __syncthreads();
        qhead = qtail;
        qtail = qtail_s;
        __syncthreads();
    }
}

// ---------------- mean aggregation over node list (device fn) ----------------
// deg from offs (cnt is destroyed by fill_wcomb)

__device__ void dev_aggregate(
    const float* __restrict__ H, float* __restrict__ Out,
    const int* __restrict__ offs, const int* __restrict__ csr,
    const int* __restrict__ order, int M, const int* __restrict__ srcmap,
    int bid0, int nb) {
    int ngroups = (M + 3) >> 2;
    int wid = threadIdx.x >> 6, lane = threadIdx.x & 63;
    for (int g = bid0; g < ngroups; g += nb) {
        int ni = g * 4 + wid;
        if (ni >= M) continue;
        int node = order[ni];
        int beg = offs[node], end = offs[node + 1];
        float ax = 0.f, ay = 0.f, bx = 0.f, by = 0.f;
        int j = beg;
        for (; j + 1 < end; j += 2) {
            int s0 = csr[j], s1 = csr[j + 1];
            int r0 = srcmap ? srcmap[s0] : s0;
            int r1 = srcmap ? srcmap[s1] : s1;
            float2 v0 = *(const float2*)(H + (size_t)r0 * HD + lane * 2);
            float2 v1 = *(const float2*)(H + (size_t)r1 * HD + lane * 2);
            ax += v0.x; ay += v0.y;
            bx += v1.x; by += v1.y;
        }
        if (j < end) {
            int s0 = csr[j];
            int r0 = srcmap ? srcmap[s0] : s0;
            float2 v0 = *(const float2*)(H + (size_t)r0 * HD + lane * 2);
            ax += v0.x; ay += v0.y;
        }
        int deg = end - beg;
        float inv = 1.0f / (float)(deg > 1 ? deg : 1);
        *(float2*)(Out + (size_t)node * HD + lane * 2) =
            make_float2((ax + bx) * inv, (ay + by) * inv);
    }
}

__global__ __launch_bounds__(256) void aggregate_list(
    const float* __restrict__ H, float* __restrict__ Out,
    const int* __restrict__ offs, const int* __restrict__ csr,
    const int* __restrict__ order, const int* __restrict__ cum, int lvl,
    const int* __restrict__ srcmap) {
    dev_aggregate(H, Out, offs, csr, order, cum[lvl], srcmap,
                  blockIdx.x, gridDim.x);
}

// ---------------- head MLP on nodes 0,1 (device fn, 256 threads) ----------------

__device__ void dev_head(
    const float* __restrict__ H,
    const float* __restrict__ W_e1, const float* __restrict__ b_e1,
    const float* __restrict__ W_e2, const float* __restrict__ b_e2,
    const float* __restrict__ W_h1, const float* __restrict__ b_h1,
    const float* __restrict__ W_h2, const float* __restrict__ b_h2,
    float* __restrict__ head_out, int kidx) {

    __shared__ float feat[384];
    __shared__ float rowo[128];
    __shared__ float sc_sh;
    int t = threadIdx.x, lane = t & 63, wv = t >> 6;

    __syncthreads();
    if (t < 128) {
        float a = H[t], b = H[128 + t];
        feat[t] = a;
        feat[128 + t] = b;
        feat[256 + t] = a * b;
    }
    __syncthreads();

    for (int r = wv; r < 128; r += 4) {
        const float* wr = W_e1 + r * 384;
        float acc = 0.f;
#pragma unroll
        for (int j = 0; j < 6; ++j)
            acc += feat[lane + 64 * j] * wr[lane + 64 * j];
        for (int off = 32; off; off >>= 1) acc += __shfl_down(acc, off);
        if (lane == 0) rowo[r] = fmaxf(acc + b_e1[r], 0.f) * W_e2[r];
    }
    __syncthreads();
    if (wv == 0) {
        float v = rowo[lane] + rowo[lane + 64];
        for (int off = 32; off; off >>= 1) v += __shfl_down(v, off);
        if (lane == 0) sc_sh = v + b_e2[0];
    }
    __syncthreads();
    float score = sc_sh;

    for (int r = wv; r < 64; r += 4) {
        const float* wh = W_h1 + r * 257;
        float acc = 0.f;
#pragma unroll
        for (int j = 0; j < 4; ++j)
            acc += feat[lane + 64 * j] * wh[lane + 64 * j];
        if (lane == 0) acc += score * wh[256];
        for (int off = 32; off; off >>= 1) acc += __shfl_down(acc, off);
        if (lane == 0) rowo[r] = fmaxf(acc + b_h1[r], 0.f) * W_h2[r];
    }
    __syncthreads();
    if (wv == 0) {
        float v = rowo[lane];
        for (int off = 32; off; off >>= 1) v += __shfl_down(v, off);
        if (lane == 0) {
            float p = 1.f / (1.f + expf(-(v + b_h2[0])));
            head_out[kidx * 2 + 0] = score;
            head_out[kidx * 2 + 1] = p;
        }
    }
    __syncthreads();
}

// ---------------- fp32 tiled GEMM over node list (+fused head on tile 0) ----------------
// rows i < M: nr = order[i]
// Out[nr][:] = relu( A1[gA(nr)] @ W1.T + A2[gB(nr)] @ W2.T + bias )

#define GBM 64
#define GBK 32

__device__ void dev_gemm(
    const float* __restrict__ A1, const float* __restrict__ A2,
    const float* __restrict__ W1, const float* __restrict__ W2,
    const float* __restrict__ bias, float* __restrict__ Out,
    const int* __restrict__ order, const int* __restrict__ gatherA,
    const int* __restrict__ gatherB, int M, int bid0, int nb,
    const float* __restrict__ W_e1, const float* __restrict__ b_e1,
    const float* __restrict__ W_e2, const float* __restrict__ b_e2,
    const float* __restrict__ W_h1, const float* __restrict__ b_h1,
    const float* __restrict__ W_h2, const float* __restrict__ b_h2,
    float* __restrict__ head_out, int head_kidx) {

    __shared__ __align__(16) float As[GBK][68];
    __shared__ __align__(16) float Ws[GBK][132];

    int ntiles = (M + GBM - 1) / GBM;
    int tid = threadIdx.x;
    int tx = tid & 15, ty = tid >> 4;
    int r0 = ty * 4;
    int c0 = tx * 4;

    for (int tile = bid0; tile < ntiles; tile += nb) {
        int row0 = tile * GBM;

        float acc[4][8];
#pragma unroll
        for (int i = 0; i < 4; ++i)
#pragma unroll
            for (int j = 0; j < 8; ++j) acc[i][j] = 0.f;

        for (int ch = 0; ch < 8; ++ch) {
            const float* Asrc = (ch < 4) ? A1 : A2;
            const float* Wsrc = (ch < 4) ? W1 : W2;
            const int* gmap = (ch < 4) ? gatherA : gatherB;
            int kbase = (ch & 3) * GBK;

#pragma unroll
            for (int it = 0; it < 2; ++it) {
                int idx = tid + it * 256;
                int m = idx >> 3, kq = idx & 7;
                int row = row0 + m;
                float4 v = make_float4(0.f, 0.f, 0.f, 0.f);
                if (row < M) {
                    int nr = order[row];
                    int ar = gmap ? gmap[nr] : nr;
                    v = *(const float4*)(Asrc + (size_t)ar * 128 + kbase + kq * 4);
                }
                As[kq * 4 + 0][m] = v.x;
                As[kq * 4 + 1][m] = v.y;
                As[kq * 4 + 2][m] = v.z;
                As[kq * 4 + 3][m] = v.w;
            }
#pragma unroll
            for (int it = 0; it < 4; ++it) {
                int idx = tid + it * 256;
                int n = idx >> 3, kq = idx & 7;
                float4 v = *(const float4*)(Wsrc + n * 128 + kbase + kq * 4);
                Ws[kq * 4 + 0][n] = v.x;
                Ws[kq * 4 + 1][n] = v.y;
                Ws[kq * 4 + 2][n] = v.z;
                Ws[kq * 4 + 3][n] = v.w;
            }
            __syncthreads();

#pragma unroll
            for (int kk = 0; kk < GBK; ++kk) {
                float4 a  = *(const float4*)&As[kk][r0];
                float4 w0 = *(const float4*)&Ws[kk][c0];
                float4 w1 = *(const float4*)&Ws[kk][c0 + 64];
                float av[4] = {a.x, a.y, a.z, a.w};
                float wv[8] = {w0.x, w0.y, w0.z, w0.w, w1.x, w1.y, w1.z, w1.w};
#pragma unroll
                for (int i = 0; i < 4; ++i)
#pragma unroll
                    for (int j = 0; j < 8; ++j)
                        acc[i][j] = fmaf(av[i], wv[j], acc[i][j]);
            }
            __syncthreads();
        }

#pragma unroll
        for (int i = 0; i < 4; ++i) {
            int row = row0 + r0 + i;
            if (row >= M) continue;
            int nr = order[row];
            float4 o0, o1;
            o0.x = fmaxf(acc[i][0] + bias[c0 + 0], 0.f);
            o0.y = fmaxf(acc[i][1] + bias[c0 + 1], 0.f);
            o0.z = fmaxf(acc[i][2] + bias[c0 + 2], 0.f);
            o0.w = fmaxf(acc[i][3] + bias[c0 + 3], 0.f);
            o1.x = fmaxf(acc[i][4] + bias[c0 + 64], 0.f);
            o1.y = fmaxf(acc[i][5] + bias[c0 + 65], 0.f);
            o1.z = fmaxf(acc[i][6] + bias[c0 + 66], 0.f);
            o1.w = fmaxf(acc[i][7] + bias[c0 + 67], 0.f);
            *(float4*)(Out + (size_t)nr * 128 + c0) = o0;
            *(float4*)(Out + (size_t)nr * 128 + c0 + 64) = o1;
        }

        // fused head: tile 0 computed rows 0,1 (= nodes 0,1) fully
        if (tile == 0 && head_kidx >= 0) {
            dev_head(Out, W_e1, b_e1, W_e2, b_e2, W_h1, b_h1, W_h2, b_h2,
                     head_out, head_kidx);
        }
    }
}

__global__ __launch_bounds__(256) void gemm_list(
    const float* __restrict__ A1, const float* __restrict__ A2,
    const float* __restrict__ W1, const float* __restrict__ W2,
    const float* __restrict__ bias, float* __restrict__ Out,
    const int* __restrict__ order, const int* __restrict__ gatherA,
    const int* __restrict__ gatherB, const int* __restrict__ cum, int lvl,
    const float* __restrict__ W_e1, const float* __restrict__ b_e1,
    const float* __restrict__ W_e2, const float* __restrict__ b_e2,
    const float* __restrict__ W_h1, const float* __restrict__ b_h1,
    const float* __restrict__ W_h2, const float* __restrict__ b_h2,
    float* __restrict__ head_out, int head_kidx) {
    dev_gemm(A1, A2, W1, W2, bias, Out, order, gatherA, gatherB, cum[lvl],
             blockIdx.x, gridDim.x,
             W_e1, b_e1, W_e2, b_e2, W_h1, b_h1, W_h2, b_h2,
             head_out, head_kidx);
}

// ---------------- tail: steps 4,5 (22 and 2 nodes) + heads + finalize ----------------

__global__ __launch_bounds__(256) void tail_small(
    float* __restrict__ HA, float* __restrict__ HB,
    const int* __restrict__ order, const int* __restrict__ offs,
    const int* __restrict__ csr, const int* __restrict__ cum,
    const float* __restrict__ W_l, const float* __restrict__ b_l,
    const float* __restrict__ W_r,
    const float* __restrict__ W_e1, const float* __restrict__ b_e1,
    const float* __restrict__ W_e2, const float* __restrict__ b_e2,
    const float* __restrict__ W_h1, const float* __restrict__ b_h1,
    const float* __restrict__ W_h2, const float* __restrict__ b_h2,
    float* __restrict__ head_out, float* __restrict__ out) {

    // k=4 on C_1
    dev_aggregate(HA, HB, offs, csr, order, cum[1], nullptr, 0, 1);
    __syncthreads();
    dev_gemm(HB, HA, W_l, W_r, b_l, HA, order, nullptr, nullptr, cum[1], 0, 1,
             W_e1, b_e1, W_e2, b_e2, W_h1, b_h1, W_h2, b_h2, head_out, 3);
    __syncthreads();
    // k=5 on C_0
    dev_aggregate(HA, HB, offs, csr, order, cum[0], nullptr, 0, 1);
    __syncthreads();
    dev_gemm(HB, HA, W_l, W_r, b_l, HA, order, nullptr, nullptr, cum[0], 0, 1,
             W_e1, b_e1, W_e2, b_e2, W_h1, b_h1, W_h2, b_h2, head_out, 4);
    __syncthreads();

    if (threadIdx.x == 0) {
        float a[LMAX];
        float p_not = 1.f, s = 0.f;
        for (int k = 0; k < LMAX; ++k) {
            float p = head_out[2 * k + 1];
            a[k] = p * p_not;
            p_not *= (1.f - p);
            s += a[k];
        }
        float inv = 1.f / (s + 1e-8f);
        float fs = 0.f, ed = 0.f;
        for (int k = 0; k < LMAX; ++k) {
            float al = a[k] * inv;
            out[2 + k] = al;
            fs += al * head_out[2 * k];
            ed += al * (float)(k + 1);
        }
        out[0] = fs;
        out[1] = ed;
    }
}

// ---------------- launch ----------------

extern "C" void kernel_launch(void* const* d_in, const int* in_sizes, int n_in,
                              void* d_out, int out_size, void* d_ws, size_t ws_size,
                              hipStream_t stream) {
    const float* x_full = (const float*)d_in[0];
    const float* W_in  = (const float*)d_in[1];
    const float* b_in  = (const float*)d_in[2];
    const float* W_l   = (const float*)d_in[3];
    const float* b_l   = (const float*)d_in[4];
    const float* W_r   = (const float*)d_in[5];
    const float* W_e1  = (const float*)d_in[6];
    const float* b_e1  = (const float*)d_in[7];
    const float* W_e2  = (const float*)d_in[8];
    const float* b_e2  = (const float*)d_in[9];
    const float* W_h1  = (const float*)d_in[10];
    const float* b_h1  = (const float*)d_in[11];
    const float* W_h2  = (const float*)d_in[12];
    const float* b_h2  = (const float*)d_in[13];
    const int* subset  = (const int*)d_in[14];
    const int* edge    = (const int*)d_in[15];
    const int* esrc = edge;
    const int* edst = edge + E_NUM;

    // workspace carve-up
    char* w = (char*)d_ws;
    float* HA = (float*)w;      w += (size_t)N_SUB * HD * 4;
    float* HB = (float*)w;      w += (size_t)N_SUB * HD * 4;
    int* cnt = (int*)w;         w += (size_t)N_SUB * 4;
    int* offs = (int*)w;        w += (size_t)(N_SUB + 64) * 4;
    int* csr = (int*)w;         w += (size_t)E_NUM * 4;
    int* level = (int*)w;       w += (size_t)N_SUB * 4;
    int* order = (int*)w;       w += (size_t)N_SUB * 4;
    int* cum = (int*)w;         w += 64;
    float* Wc1 = (float*)w;     w += 128 * 128 * 4;
    float* Wc2 = (float*)w;     w += 128 * 128 * 4;
    float* bc = (float*)w;      w += 512;
    float* head_out = (float*)w; w += 256;

    hipMemsetAsync(cnt, 0, (size_t)N_SUB * 4, stream);
    count_deg<<<NB_E, 256, 0, stream>>>(edst, cnt);
    scan_plus<<<1, 1024, 0, stream>>>(cnt, offs, level);
    fill_wcomb<<<NB_E + WCOMB_BLKS, 256, 0, stream>>>(
        esrc, edst, offs, cnt, csr, W_l, W_r, W_in, b_in, b_l, Wc1, Wc2, bc);
    bfs_compact<<<1, 1024, 0, stream>>>(offs, csr, level, order, cum);

    // k=1 on C_4 (linearity: aggregate raw x, combined weights)
    aggregate_list<<<2048, 256, 0, stream>>>(
        x_full, HB, offs, csr, order, cum, 4, subset);
    gemm_list<<<512, 256, 0, stream>>>(
        HB, x_full, Wc1, Wc2, bc, HA, order, nullptr, subset, cum, 4,
        W_e1, b_e1, W_e2, b_e2, W_h1, b_h1, W_h2, b_h2, head_out, 0);
    // k=2 on C_3
    aggregate_list<<<64, 256, 0, stream>>>(
        HA, HB, offs, csr, order, cum, 3, nullptr);
    gemm_list<<<48, 256, 0, stream>>>(
        HB, HA, W_l, W_r, b_l, HA, order, nullptr, nullptr, cum, 3,
        W_e1, b_e1, W_e2, b_e2, W_h1, b_h1, W_h2, b_h2, head_out, 1);
    // k=3 on C_2
    aggregate_list<<<16, 256, 0, stream>>>(
        HA, HB, offs, csr, order, cum, 2, nullptr);
    gemm_list<<<4, 256, 0, stream>>>(
        HB, HA, W_l, W_r, b_l, HA, order, nullptr, nullptr, cum, 2,
        W_e1, b_e1, W_e2, b_e2, W_h1, b_h1, W_h2, b_h2, head_out, 2);
    // k=4,5 + finalize
    tail_small<<<1, 256, 0, stream>>>(
        HA, HB, order, offs, csr, cum,
        W_l, b_l, W_r, W_e1, b_e1, W_e2, b_e2, W_h1, b_h1, W_h2, b_h2,
        head_out, (float*)d_out);
}